// Round 1
// baseline (175.116 us; speedup 1.0000x reference)
//
#include <hip/hip_runtime.h>
#include <hip/hip_bf16.h>

constexpr int NN = 1024;   // nodes
constexpr int DD = 128;    // NODE_DIM == HID
constexpr int EDIM = 32;   // EDGE_DIM
constexpr int NR = 16;     // NREL

using short4v = __attribute__((ext_vector_type(4))) short;
using short8v = __attribute__((ext_vector_type(8))) short;
using f32x4   = __attribute__((ext_vector_type(4))) float;

__device__ __forceinline__ short f2bf(float x) {
  __hip_bfloat16 h = __float2bfloat16(x);   // RNE
  return __builtin_bit_cast(short, h);
}

// ---------------- K1: rsinv[i] = 1/(rowsum(adj[i]) + 1e-6) ----------------
__global__ __launch_bounds__(256) void k_rowsum(const float* __restrict__ adj,
                                                float* __restrict__ rsinv) {
  int i = blockIdx.x, t = threadIdx.x;
  const float4* row = (const float4*)(adj + (size_t)i * NN);
  float4 v = row[t];                       // 256 threads * 4 = 1024
  float s = v.x + v.y + v.z + v.w;
  #pragma unroll
  for (int off = 32; off > 0; off >>= 1) s += __shfl_down(s, off, 64);
  __shared__ float red[4];
  if ((t & 63) == 0) red[t >> 6] = s;
  __syncthreads();
  if (t == 0) rsinv[i] = 1.0f / (red[0] + red[1] + red[2] + red[3] + 1e-6f);
}

// ---------------- K2a: partial[kc][i][h] = sum_{k in chunk} adj[i][k]*X[k][h] ----------------
// grid = 64 i-tiles * 8 k-chunks = 512 blocks, 256 threads
__global__ __launch_bounds__(256) void k_adjgemm(const float* __restrict__ adj,
                                                 const float* __restrict__ X,
                                                 float* __restrict__ part) {
  __shared__ float sadj[16][128];          // 8 KB
  int t = threadIdx.x;
  int ic = blockIdx.x & 63, kc = blockIdx.x >> 6;
  int i0 = ic * 16, k0 = kc * 128;
  {
    int il = t >> 4;                       // 0..15
    int kl = (t & 15) * 8;                 // 0..120
    const float4* src = (const float4*)(adj + (size_t)(i0 + il) * NN + k0 + kl);
    *(float4*)&sadj[il][kl]     = src[0];
    *(float4*)&sadj[il][kl + 4] = src[1];
  }
  __syncthreads();
  int h = t & 127, ii = t >> 7;            // ii in {0,1}
  float acc[8] = {0,0,0,0,0,0,0,0};
  for (int k = 0; k < 128; k += 4) {
    float x0 = X[(size_t)(k0 + k) * DD + h];
    float x1 = X[(size_t)(k0 + k + 1) * DD + h];
    float x2 = X[(size_t)(k0 + k + 2) * DD + h];
    float x3 = X[(size_t)(k0 + k + 3) * DD + h];
    #pragma unroll
    for (int m = 0; m < 8; ++m) {
      int il = ii + m * 2;
      float4 a = *(const float4*)&sadj[il][k];   // broadcast across the wave
      acc[m] += a.x * x0 + a.y * x1 + a.z * x2 + a.w * x3;
    }
  }
  #pragma unroll
  for (int m = 0; m < 8; ++m)
    part[((size_t)kc * NN + (i0 + ii + m * 2)) * DD + h] = acc[m];
}

// ---------------- K2b: agg[i][h] = rsinv[i] * sum_kc partial[kc][i][h] ----------------
__global__ __launch_bounds__(256) void k_aggfin(const float* __restrict__ part,
                                                const float* __restrict__ rsinv,
                                                float* __restrict__ agg) {
  int idx = blockIdx.x * 256 + threadIdx.x;   // 131072 total
  int i = idx >> 7;
  float s = 0.f;
  #pragma unroll
  for (int kc = 0; kc < 8; ++kc) s += part[(size_t)kc * NN * DD + idx];
  agg[idx] = s * rsinv[i];
}

// ---------------- K3/K5: out[i][h] = relu( X[i]@W[h][0:128] + Y[i]@W[h][128:256] + b[h] ), W ld=256
__global__ __launch_bounds__(256) void k_dense2(const float* __restrict__ X,
                                                const float* __restrict__ Y,
                                                const float* __restrict__ W,
                                                const float* __restrict__ b,
                                                float* __restrict__ out) {
  int t = threadIdx.x;
  int i = blockIdx.x * 2 + (t >> 7), h = t & 127;
  const float4* xr = (const float4*)(X + (size_t)i * DD);
  const float4* yr = (const float4*)(Y + (size_t)i * DD);
  const float4* w1 = (const float4*)(W + (size_t)h * 256);
  const float4* w2 = (const float4*)(W + (size_t)h * 256 + DD);
  float acc = b[h];
  #pragma unroll 8
  for (int k = 0; k < 32; ++k) {
    float4 x = xr[k], w = w1[k];
    acc += x.x * w.x + x.y * w.y + x.z * w.z + x.w * w.w;
  }
  #pragma unroll 8
  for (int k = 0; k < 32; ++k) {
    float4 y = yr[k], w = w2[k];
    acc += y.x * w.x + y.y * w.y + y.z * w.z + y.w * w.w;
  }
  out[(size_t)i * DD + h] = fmaxf(acc, 0.f);
}

// ---------------- K6: Aib[i][h] = h2[i]@Wa[h] + b_c1[h];  Bmat[i][h] = h2[i]@Wb[h] ----------------
__global__ __launch_bounds__(256) void k_ab(const float* __restrict__ h2,
                                            const float* __restrict__ Wc1,
                                            const float* __restrict__ bc1,
                                            float* __restrict__ Aib,
                                            float* __restrict__ Bmat) {
  int t = threadIdx.x;
  int i = blockIdx.x * 2 + (t >> 7), h = t & 127;
  const float4* xr = (const float4*)(h2 + (size_t)i * DD);
  const float4* wa = (const float4*)(Wc1 + (size_t)h * 288);
  const float4* wb = (const float4*)(Wc1 + (size_t)h * 288 + 128);
  float aa = bc1[h], bb = 0.f;
  #pragma unroll 8
  for (int k = 0; k < 32; ++k) {
    float4 x = xr[k];
    float4 a = wa[k], b2 = wb[k];
    aa += x.x * a.x + x.y * a.y + x.z * a.z + x.w * a.w;
    bb += x.x * b2.x + x.y * b2.y + x.z * b2.z + x.w * b2.w;
  }
  Aib[(size_t)i * DD + h] = aa;
  Bmat[(size_t)i * DD + h] = bb;
}

// ---------------- K7: fused edge stage ----------------
// pre[i,j,h] = Aib[i,h] + Bmat[j,h] + edge[i,j,:]@We[h,:]ᵀ   (b_c1 folded in Aib)
// out[i,j,r] = (i==j) ? 0 : relu(pre)@Wc2[r,:]ᵀ + b_c2[r]
// grid: blockIdx = ib*4 + jq, ib in [0,256) covers 4 i's, jq quarter of j.
// wave w handles j0 = jq*256 + w*64 + tg*16, tg=0..3; 16 pairs per MFMA group.
__global__ __launch_bounds__(256) void k_edge(const float* __restrict__ edge,
                                              const float* __restrict__ Wc1,
                                              const float* __restrict__ Wc2,
                                              const float* __restrict__ bc2,
                                              const float* __restrict__ Aib,
                                              const float* __restrict__ Bmat,
                                              float* __restrict__ out) {
  __shared__ __align__(16) short plds[4][2048];  // per-wave 16x128 bf16 tile
  int tid = threadIdx.x;
  int w = tid >> 6, lane = tid & 63;
  int c = lane & 15, g = lane >> 4;
  int ib = blockIdx.x >> 2, jq = blockIdx.x & 3;
  int sw = (c & 7) << 4;                          // XOR swizzle (G4)
  char* myp = ((char*)plds) + w * 4096;

  // Preload We fragments: A1[m=c][k=8g+j] = Wc1[16n+c][256 + 8g+j]
  short8v weF[8];
  #pragma unroll
  for (int n = 0; n < 8; ++n) {
    const float* p = Wc1 + (size_t)(16 * n + c) * 288 + 256 + 8 * g;
    float4 f0 = *(const float4*)p;
    float4 f1 = *(const float4*)(p + 4);
    short8v s;
    s[0]=f2bf(f0.x); s[1]=f2bf(f0.y); s[2]=f2bf(f0.z); s[3]=f2bf(f0.w);
    s[4]=f2bf(f1.x); s[5]=f2bf(f1.y); s[6]=f2bf(f1.z); s[7]=f2bf(f1.w);
    weF[n] = s;
  }
  // Preload Wc2 fragments: A2[m=c][k=32kk+8g+j] = Wc2[c][32kk+8g+j]
  short8v wcF[4];
  #pragma unroll
  for (int kk = 0; kk < 4; ++kk) {
    const float* p = Wc2 + (size_t)c * DD + 32 * kk + 8 * g;
    float4 f0 = *(const float4*)p;
    float4 f1 = *(const float4*)(p + 4);
    short8v s;
    s[0]=f2bf(f0.x); s[1]=f2bf(f0.y); s[2]=f2bf(f0.z); s[3]=f2bf(f0.w);
    s[4]=f2bf(f1.x); s[5]=f2bf(f1.y); s[6]=f2bf(f1.z); s[7]=f2bf(f1.w);
    wcF[kk] = s;
  }
  float4 bc2v = *(const float4*)(bc2 + 4 * g);

  for (int tg = 0; tg < 4; ++tg) {
    int j0 = jq * 256 + w * 64 + tg * 16;
    int j = j0 + c;
    // Bmat values for this lane's pair: bjv[n][r] = Bmat[j][16n+4g+r]
    float4 bjv[8];
    #pragma unroll
    for (int n = 0; n < 8; ++n)
      bjv[n] = *(const float4*)(Bmat + (size_t)j * DD + 16 * n + 4 * g);

    for (int i2 = 0; i2 < 4; ++i2) {
      int i = ib * 4 + i2;
      // edge fragment: B1[k=8g+j'][col=c] = edge[i][j][8g+j']
      const float* ep = edge + ((size_t)i * NN + j) * EDIM + 8 * g;
      float4 e0 = *(const float4*)ep;
      float4 e1 = *(const float4*)(ep + 4);
      short8v ef;
      ef[0]=f2bf(e0.x); ef[1]=f2bf(e0.y); ef[2]=f2bf(e0.z); ef[3]=f2bf(e0.w);
      ef[4]=f2bf(e1.x); ef[5]=f2bf(e1.y); ef[6]=f2bf(e1.z); ef[7]=f2bf(e1.w);

      // GEMM1: D1[h'=4g+r][pair=c] for h = 16n + h'; C-in = Aib + Bmat
      #pragma unroll
      for (int n = 0; n < 8; ++n) {
        float4 av = *(const float4*)(Aib + (size_t)i * DD + 16 * n + 4 * g);
        f32x4 acc;
        acc[0] = av.x + bjv[n].x;
        acc[1] = av.y + bjv[n].y;
        acc[2] = av.z + bjv[n].z;
        acc[3] = av.w + bjv[n].w;
        acc = __builtin_amdgcn_mfma_f32_16x16x32_bf16(weF[n], ef, acc, 0, 0, 0);
        short4v pk;
        pk[0] = f2bf(fmaxf(acc[0], 0.f));
        pk[1] = f2bf(fmaxf(acc[1], 0.f));
        pk[2] = f2bf(fmaxf(acc[2], 0.f));
        pk[3] = f2bf(fmaxf(acc[3], 0.f));
        // row c, h-bytes (32n+8g), XOR-swizzled; 4 consecutive h per lane
        *(short4v*)(myp + c * 256 + ((32 * n + 8 * g) ^ sw)) = pk;
      }
      // GEMM2: D2[rel=4g+r][pair=c]; C-in = b_c2
      f32x4 acc2;
      acc2[0] = bc2v.x; acc2[1] = bc2v.y; acc2[2] = bc2v.z; acc2[3] = bc2v.w;
      #pragma unroll
      for (int kk = 0; kk < 4; ++kk) {
        short8v pb = *(short8v*)(myp + c * 256 + ((64 * kk + 16 * g) ^ sw));
        acc2 = __builtin_amdgcn_mfma_f32_16x16x32_bf16(wcF[kk], pb, acc2, 0, 0, 0);
      }
      bool diag = (j == i);
      float4 o;
      o.x = diag ? 0.f : acc2[0];
      o.y = diag ? 0.f : acc2[1];
      o.z = diag ? 0.f : acc2[2];
      o.w = diag ? 0.f : acc2[3];
      *(float4*)(out + ((size_t)i * NN + j) * NR + 4 * g) = o;
    }
  }
}

extern "C" void kernel_launch(void* const* d_in, const int* in_sizes, int n_in,
                              void* d_out, int out_size, void* d_ws, size_t ws_size,
                              hipStream_t stream) {
  const float* node_feat = (const float*)d_in[0];
  const float* edge_feat = (const float*)d_in[1];
  const float* adj  = (const float*)d_in[2];
  const float* W_g1 = (const float*)d_in[3];
  const float* b_g1 = (const float*)d_in[4];
  const float* W_g2 = (const float*)d_in[5];
  const float* b_g2 = (const float*)d_in[6];
  const float* W_c1 = (const float*)d_in[7];
  const float* b_c1 = (const float*)d_in[8];
  const float* W_c2 = (const float*)d_in[9];
  const float* b_c2 = (const float*)d_in[10];
  float* out = (float*)d_out;

  float* ws    = (float*)d_ws;
  float* rsinv = ws;                        // 1024
  float* part  = ws + 1024;                 // 8*1024*128 = 1048576
  float* agg   = part + 8 * NN * DD;        // 131072
  float* h1    = agg + NN * DD;             // 131072
  float* h2    = h1 + NN * DD;              // 131072
  float* Aib   = h2 + NN * DD;              // 131072
  float* Bmat  = Aib + NN * DD;             // 131072   (total ~6.5 MB)

  k_rowsum<<<NN, 256, 0, stream>>>(adj, rsinv);
  // layer 1
  k_adjgemm<<<512, 256, 0, stream>>>(adj, node_feat, part);
  k_aggfin<<<512, 256, 0, stream>>>(part, rsinv, agg);
  k_dense2<<<512, 256, 0, stream>>>(node_feat, agg, W_g1, b_g1, h1);
  // layer 2
  k_adjgemm<<<512, 256, 0, stream>>>(adj, h1, part);
  k_aggfin<<<512, 256, 0, stream>>>(part, rsinv, agg);
  k_dense2<<<512, 256, 0, stream>>>(h1, agg, W_g2, b_g2, h2);
  // head precompute
  k_ab<<<512, 256, 0, stream>>>(h2, W_c1, b_c1, Aib, Bmat);
  // fused edge stage
  k_edge<<<1024, 256, 0, stream>>>(edge_feat, W_c1, W_c2, b_c2, Aib, Bmat, out);
}